// Round 3
// baseline (1185.037 us; speedup 1.0000x reference)
//
#include <hip/hip_runtime.h>
#include <math.h>

#define Bn  8
#define Cn  64
#define Hn  192
#define Wn  256
#define HWc (Hn*Wn)
#define CHWc (Cn*HWc)
#define NCH 32
#define CWc 8

#define AGENT __HIP_MEMORY_SCOPE_AGENT
#define RLX   __ATOMIC_RELAXED

// [b][ch][side][wave] = last row pos completed (monotonic); re-zeroed each launch
__device__ int   g_flagsM[Bn*NCH*2*4];
// [b][ch][side(0=left edge,1=right edge)][parity][co]
__device__ float g_halo[Bn*NCH*2*2*Cn];

__global__ void zero_flags_k() {
    int i = blockIdx.x * 256 + threadIdx.x;
    if (i < Bn*NCH*2*4) g_flagsM[i] = 0;
}

__global__ __launch_bounds__(256, 1) void seqconv_k(
    const float* __restrict__ X, const float* __restrict__ Wt,
    const float* __restrict__ Bias, float* __restrict__ Out)
{
    const int tid  = threadIdx.x;
    const int lane = tid & 63;
    const int wq   = tid >> 6;          // wave id: co-high
    const int co_l = lane & 15;
    const int cig  = lane >> 4;         // ci-group within wave (0..3)
    const int co   = wq * 16 + co_l;
    const int ci0  = cig * 16;
    const int wlo  = 4 * (cig & 1) + (cig & 2);   // final w-pair base: 0,4,2,6
    const int bid  = blockIdx.x;
    const int b    = bid & 7;           // batch -> XCD bid%8: all chunks of b share an XCD
    const int ch   = bid >> 3;          // width chunk 0..31
    const int w0   = ch * CWc;
    const int rco  = tid >> 3, rwl = tid & 7;  // coalesced Out-write mapping

    __shared__ __align__(16) float xin[3][12][68];  // [slot][col 0..9][ci]

    const float* Xb = X  + (size_t)b * CHWc;
    float*       Ob = Out + (size_t)b * CHWc;

    // ---- weights: straight-line contiguous load -> registers (no spill)
    // thread needs Wt[co][ci0..ci0+15][:][:] = 144 contiguous floats
    float wreg[144];
    {
        const float4* wsrc = reinterpret_cast<const float4*>(Wt + (size_t)co * 576 + ci0 * 9);
        #pragma unroll
        for (int t = 0; t < 36; ++t) {
            float4 v = wsrc[t];
            wreg[4*t]   = v.x; wreg[4*t+1] = v.y;
            wreg[4*t+2] = v.z; wreg[4*t+3] = v.w;
        }
    }
    const float breg = Bias[co];

    // ---- per-thread staging tuples for one row (640 = 64ci x 10col)
    int  s_col[3], s_ci[3];
    bool s_act[3], s_ok[3];
    size_t s_off[3];
    #pragma unroll
    for (int k = 0; k < 3; ++k) {
        int idx = tid + 256*k;
        bool act = idx < 640;
        int ci  = act ? idx / 10 : 0;
        int col = act ? idx % 10 : 0;
        int gw  = w0 - 1 + col;
        bool ok = act && gw >= 0 && gw < Wn;
        s_ci[k] = ci; s_col[k] = col; s_act[k] = act; s_ok[k] = ok;
        s_off[k] = (size_t)ci * HWc + (ok ? gw : 0);
    }

    // ---- rows 0,1 into slots 0,1 (original == updated), copy Out rows 0,1
    #pragma unroll
    for (int r = 0; r < 2; ++r)
        #pragma unroll
        for (int k = 0; k < 3; ++k)
            if (s_act[k])
                xin[r][s_col[k]][s_ci[k]] = s_ok[k] ? Xb[s_off[k] + (size_t)r * Wn] : 0.f;

    for (int idx = tid; idx < 2*Cn*CWc; idx += 256) {
        int r = idx >> 9, rem = idx & 511, ci = rem >> 3, wl = rem & 7;
        size_t o = (size_t)ci * HWc + (size_t)r * Wn + w0 + wl;
        Ob[o] = Xb[o];
    }

    // prefetch original row 2
    float pf[3];
    #pragma unroll
    for (int k = 0; k < 3; ++k)
        pf[k] = s_ok[k] ? Xb[s_off[k] + (size_t)2 * Wn] : 0.f;

    __syncthreads();

    for (int pos = 2; pos < Hn; ++pos) {
        const int sA = (pos - 2) % 3, sB = (pos - 1) % 3, sC = pos % 3;

        // A: commit prefetched original row pos (boundary cols already 0 via s_ok)
        #pragma unroll
        for (int k = 0; k < 3; ++k)
            if (s_act[k]) xin[sC][s_col[k]][s_ci[k]] = pf[k];

        // B: poll neighbor per-wave flags, pull updated halo cols of row pos-1
        if (pos >= 3) {
            if (tid < 64) {
                if (ch > 0) {
                    const int fb = ((b*NCH + ch - 1)*2 + 1)*4;   // left nb's right-edge flags
                    for (;;) {
                        int f0 = __hip_atomic_load(&g_flagsM[fb+0], RLX, AGENT);
                        int f1 = __hip_atomic_load(&g_flagsM[fb+1], RLX, AGENT);
                        int f2 = __hip_atomic_load(&g_flagsM[fb+2], RLX, AGENT);
                        int f3 = __hip_atomic_load(&g_flagsM[fb+3], RLX, AGENT);
                        if (min(min(f0,f1),min(f2,f3)) >= pos-1) break;
                    }
                    xin[sB][0][lane] = __hip_atomic_load(
                        &g_halo[(((b*NCH + ch - 1)*2 + 1)*2 + ((pos-1)&1))*Cn + lane], RLX, AGENT);
                }
            } else if (tid < 128) {
                if (ch < NCH - 1) {
                    const int fb = ((b*NCH + ch + 1)*2 + 0)*4;   // right nb's left-edge flags
                    for (;;) {
                        int f0 = __hip_atomic_load(&g_flagsM[fb+0], RLX, AGENT);
                        int f1 = __hip_atomic_load(&g_flagsM[fb+1], RLX, AGENT);
                        int f2 = __hip_atomic_load(&g_flagsM[fb+2], RLX, AGENT);
                        int f3 = __hip_atomic_load(&g_flagsM[fb+3], RLX, AGENT);
                        if (min(min(f0,f1),min(f2,f3)) >= pos-1) break;
                    }
                    xin[sB][9][lane] = __hip_atomic_load(
                        &g_halo[(((b*NCH + ch + 1)*2 + 0)*2 + ((pos-1)&1))*Cn + lane], RLX, AGENT);
                }
            }
        }
        __syncthreads();  // SYNC1

        // C: prefetch next original row (hides HBM latency under compute)
        {
            const int nr = (pos + 1 < Hn) ? pos + 1 : pos;
            #pragma unroll
            for (int k = 0; k < 3; ++k)
                pf[k] = s_ok[k] ? Xb[s_off[k] + (size_t)nr * Wn] : 0.f;
        }

        // D: deferred coalesced Out write of row pos-1 (off critical path)
        #pragma unroll
        for (int h = 0; h < 2; ++h) {
            const int cw = rco + 32*h;
            Ob[(size_t)cw * HWc + (size_t)(pos-1) * Wn + w0 + rwl] = xin[sB][rwl + 1][cw];
        }

        // E: partials over my 16 ci for all 8 w (weights in registers)
        float acc[8] = {0.f,0.f,0.f,0.f,0.f,0.f,0.f,0.f};
        #pragma unroll
        for (int kh = 0; kh < 3; ++kh) {
            const float* xs = (kh == 0) ? &xin[sA][0][0] : (kh == 1) ? &xin[sB][0][0] : &xin[sC][0][0];
            #pragma unroll
            for (int col = 0; col < 10; ++col) {
                float4 a0 = *reinterpret_cast<const float4*>(xs + col*68 + ci0);
                float4 a1 = *reinterpret_cast<const float4*>(xs + col*68 + ci0 + 4);
                float4 a2 = *reinterpret_cast<const float4*>(xs + col*68 + ci0 + 8);
                float4 a3 = *reinterpret_cast<const float4*>(xs + col*68 + ci0 + 12);
                const float xv[16] = {a0.x,a0.y,a0.z,a0.w, a1.x,a1.y,a1.z,a1.w,
                                      a2.x,a2.y,a2.z,a2.w, a3.x,a3.y,a3.z,a3.w};
                #pragma unroll
                for (int i = 0; i < 16; ++i)
                    #pragma unroll
                    for (int kw = 0; kw < 3; ++kw) {
                        const int w = col - kw;
                        if (w >= 0 && w < 8)
                            acc[w] = fmaf(wreg[i*9 + kh*3 + kw], xv[i], acc[w]);
                    }
            }
        }

        // F: intra-wave reduce-scatter over ci-groups (no LDS, no barrier)
        const bool hiw = (cig & 1) != 0;
        float p0, p1, p2, p3;
        {
            float s0 = hiw ? acc[0] : acc[4];
            float s1 = hiw ? acc[1] : acc[5];
            float s2 = hiw ? acc[2] : acc[6];
            float s3 = hiw ? acc[3] : acc[7];
            float r0 = __shfl_xor(s0, 16, 64);
            float r1 = __shfl_xor(s1, 16, 64);
            float r2 = __shfl_xor(s2, 16, 64);
            float r3 = __shfl_xor(s3, 16, 64);
            p0 = (hiw ? acc[4] : acc[0]) + r0;
            p1 = (hiw ? acc[5] : acc[1]) + r1;
            p2 = (hiw ? acc[6] : acc[2]) + r2;
            p3 = (hiw ? acc[7] : acc[3]) + r3;
        }
        const bool hi2 = (cig & 2) != 0;
        float q0, q1;
        {
            float s0 = hi2 ? p0 : p2;
            float s1 = hi2 ? p1 : p3;
            float r0 = __shfl_xor(s0, 32, 64);
            float r1 = __shfl_xor(s1, 32, 64);
            q0 = (hi2 ? p2 : p0) + r0;
            q1 = (hi2 ? p3 : p1) + r1;
        }
        // q0,q1 = conv sums for w = wlo, wlo+1 at output channel co

        const float y0  = q0 + breg, y1 = q1 + breg;
        const float ov0 = xin[sC][wlo + 1][co];
        const float ov1 = xin[sC][wlo + 2][co];
        const float nv0 = ov0 + tanhf(y0);
        const float nv1 = ov1 + tanhf(y1);

        // edge exports (w==0 lanes: cig0; w==7 lanes: cig3)
        if (cig == 0 && ch > 0)
            __hip_atomic_store(&g_halo[(((b*NCH + ch)*2 + 0)*2 + (pos&1))*Cn + co], nv0, RLX, AGENT);
        if (cig == 3 && ch < NCH - 1)
            __hip_atomic_store(&g_halo[(((b*NCH + ch)*2 + 1)*2 + (pos&1))*Cn + co], nv1, RLX, AGENT);

        // update row pos in LDS (visible to block at SYNC2)
        xin[sC][wlo + 1][co] = nv0;
        xin[sC][wlo + 2][co] = nv1;

        // per-wave release: halo stores complete at coherence point, then flag
        asm volatile("s_waitcnt vmcnt(0)" ::: "memory");
        if (lane == 0 && ch > 0)
            __hip_atomic_store(&g_flagsM[((b*NCH + ch)*2 + 0)*4 + wq], pos, RLX, AGENT);
        if (lane == 48 && ch < NCH - 1)
            __hip_atomic_store(&g_flagsM[((b*NCH + ch)*2 + 1)*4 + wq], pos, RLX, AGENT);

        __syncthreads();  // SYNC2
    }

    // final row Out write
    #pragma unroll
    for (int h = 0; h < 2; ++h) {
        const int cw = rco + 32*h;
        Ob[(size_t)cw * HWc + (size_t)(Hn-1) * Wn + w0 + rwl] = xin[(Hn-1)%3][rwl + 1][cw];
    }
}

extern "C" void kernel_launch(void* const* d_in, const int* in_sizes, int n_in,
                              void* d_out, int out_size, void* d_ws, size_t ws_size,
                              hipStream_t stream) {
    const float* X    = (const float*)d_in[0];
    const float* Wt   = (const float*)d_in[1];
    const float* Bias = (const float*)d_in[2];
    float*       Out  = (float*)d_out;

    hipLaunchKernelGGL(zero_flags_k, dim3(8), dim3(256), 0, stream);

    void* args[] = {(void*)&X, (void*)&Wt, (void*)&Bias, (void*)&Out};
    hipError_t e = hipLaunchCooperativeKernel((void*)seqconv_k, dim3(Bn*NCH), dim3(256),
                                              args, 0, stream);
    if (e != hipSuccess) {
        hipLaunchKernelGGL(seqconv_k, dim3(Bn*NCH), dim3(256), 0, stream, X, Wt, Bias, Out);
    }
}

// Round 4
// 1169.692 us; speedup vs baseline: 1.0131x; 1.0131x over previous
//
#include <hip/hip_runtime.h>
#include <math.h>
#include <utility>

#define Bn  8
#define Cn  64
#define Hn  192
#define Wn  256
#define HWc (Hn*Wn)
#define CHWc (Cn*HWc)
#define NCH 32
#define CWc 8

#define AGENT __HIP_MEMORY_SCOPE_AGENT
#define RLX   __ATOMIC_RELAXED

// compile-time loop: frontend emits constant indices (SROA-friendly, rule #20)
template <int... Is, class F>
__device__ __forceinline__ void sf_impl(F&& f, std::integer_sequence<int, Is...>) {
    (f(std::integral_constant<int, Is>{}), ...);
}
template <int N, class F>
__device__ __forceinline__ void static_for(F&& f) {
    sf_impl(f, std::make_integer_sequence<int, N>{});
}

// [b][ch][side][wave] = last row pos completed (monotonic); re-zeroed each launch
__device__ int   g_flagsM[Bn*NCH*2*4];
// [b][ch][side(0=left edge,1=right edge)][parity][co]
__device__ float g_halo[Bn*NCH*2*2*Cn];

__global__ void zero_flags_k() {
    int i = blockIdx.x * 256 + threadIdx.x;
    if (i < Bn*NCH*2*4) g_flagsM[i] = 0;
}

__global__ __launch_bounds__(256, 1) void seqconv_k(
    const float* __restrict__ X, const float* __restrict__ Wt,
    const float* __restrict__ Bias, float* __restrict__ Out)
{
    const int tid  = threadIdx.x;
    const int lane = tid & 63;
    const int wq   = tid >> 6;          // wave id: co-high
    const int co_l = lane & 15;
    const int cig  = lane >> 4;         // ci-group within wave (0..3)
    const int co   = wq * 16 + co_l;
    const int ci0  = cig * 16;
    const int wlo  = 4 * (cig & 1) + (cig & 2);   // final w-pair base: 0,4,2,6
    const int bid  = blockIdx.x;
    const int b    = bid & 7;           // batch -> XCD bid%8: all chunks of b share an XCD
    const int ch   = bid >> 3;          // width chunk 0..31
    const int w0   = ch * CWc;
    const int rco  = tid >> 3, rwl = tid & 7;  // coalesced Out-write mapping

    __shared__ __align__(16) float xin[3][12][68];  // [slot][col 0..9][ci]

    const float* Xb = X  + (size_t)b * CHWc;
    float*       Ob = Out + (size_t)b * CHWc;

    // ---- weights -> registers, ALL indices compile-time constants
    float wreg[144];
    {
        const float4* wsrc = reinterpret_cast<const float4*>(Wt + (size_t)co * 576 + ci0 * 9);
        static_for<36>([&](auto T) {
            constexpr int t = T.value;
            float4 v = wsrc[t];
            wreg[4*t]   = v.x; wreg[4*t+1] = v.y;
            wreg[4*t+2] = v.z; wreg[4*t+3] = v.w;
        });
    }
    const float breg = Bias[co];

    // ---- per-thread staging tuples for one row (640 = 64ci x 10col)
    int  s_col[3], s_ci[3];
    bool s_act[3], s_ok[3];
    size_t s_off[3];
    static_for<3>([&](auto K) {
        constexpr int k = K.value;
        int idx = tid + 256*k;
        bool act = idx < 640;
        int ci  = act ? idx / 10 : 0;
        int col = act ? idx % 10 : 0;
        int gw  = w0 - 1 + col;
        bool ok = act && gw >= 0 && gw < Wn;
        s_ci[k] = ci; s_col[k] = col; s_act[k] = act; s_ok[k] = ok;
        s_off[k] = (size_t)ci * HWc + (ok ? gw : 0);
    });

    // ---- rows 0,1 into slots 0,1 (original == updated), copy Out rows 0,1
    static_for<2>([&](auto R) {
        constexpr int r = R.value;
        static_for<3>([&](auto K) {
            constexpr int k = K.value;
            if (s_act[k])
                xin[r][s_col[k]][s_ci[k]] = s_ok[k] ? Xb[s_off[k] + (size_t)r * Wn] : 0.f;
        });
    });

    for (int idx = tid; idx < 2*Cn*CWc; idx += 256) {
        int r = idx >> 9, rem = idx & 511, ci = rem >> 3, wl = rem & 7;
        size_t o = (size_t)ci * HWc + (size_t)r * Wn + w0 + wl;
        Ob[o] = Xb[o];
    }

    // prefetch original row 2
    float pf[3];
    static_for<3>([&](auto K) {
        constexpr int k = K.value;
        pf[k] = s_ok[k] ? Xb[s_off[k] + (size_t)2 * Wn] : 0.f;
    });

    __syncthreads();

    for (int pos = 2; pos < Hn; ++pos) {
        const int sA = (pos - 2) % 3, sB = (pos - 1) % 3, sC = pos % 3;

        // A: commit prefetched original row pos (boundary cols already 0 via s_ok)
        static_for<3>([&](auto K) {
            constexpr int k = K.value;
            if (s_act[k]) xin[sC][s_col[k]][s_ci[k]] = pf[k];
        });

        // B: poll neighbor per-wave flags, pull updated halo cols of row pos-1
        if (pos >= 3) {
            if (tid < 64) {
                if (ch > 0) {
                    const int fb = ((b*NCH + ch - 1)*2 + 1)*4;   // left nb's right-edge flags
                    for (;;) {
                        int f0 = __hip_atomic_load(&g_flagsM[fb+0], RLX, AGENT);
                        int f1 = __hip_atomic_load(&g_flagsM[fb+1], RLX, AGENT);
                        int f2 = __hip_atomic_load(&g_flagsM[fb+2], RLX, AGENT);
                        int f3 = __hip_atomic_load(&g_flagsM[fb+3], RLX, AGENT);
                        if (min(min(f0,f1),min(f2,f3)) >= pos-1) break;
                    }
                    xin[sB][0][lane] = __hip_atomic_load(
                        &g_halo[(((b*NCH + ch - 1)*2 + 1)*2 + ((pos-1)&1))*Cn + lane], RLX, AGENT);
                }
            } else if (tid < 128) {
                if (ch < NCH - 1) {
                    const int fb = ((b*NCH + ch + 1)*2 + 0)*4;   // right nb's left-edge flags
                    for (;;) {
                        int f0 = __hip_atomic_load(&g_flagsM[fb+0], RLX, AGENT);
                        int f1 = __hip_atomic_load(&g_flagsM[fb+1], RLX, AGENT);
                        int f2 = __hip_atomic_load(&g_flagsM[fb+2], RLX, AGENT);
                        int f3 = __hip_atomic_load(&g_flagsM[fb+3], RLX, AGENT);
                        if (min(min(f0,f1),min(f2,f3)) >= pos-1) break;
                    }
                    xin[sB][9][lane] = __hip_atomic_load(
                        &g_halo[(((b*NCH + ch + 1)*2 + 0)*2 + ((pos-1)&1))*Cn + lane], RLX, AGENT);
                }
            }
        }
        __syncthreads();  // SYNC1

        // C: prefetch next original row (hides HBM latency under compute)
        {
            const int nr = (pos + 1 < Hn) ? pos + 1 : pos;
            static_for<3>([&](auto K) {
                constexpr int k = K.value;
                pf[k] = s_ok[k] ? Xb[s_off[k] + (size_t)nr * Wn] : 0.f;
            });
        }

        // D: deferred coalesced Out write of row pos-1 (off critical path)
        static_for<2>([&](auto Hh) {
            constexpr int h = Hh.value;
            const int cw = rco + 32*h;
            Ob[(size_t)cw * HWc + (size_t)(pos-1) * Wn + w0 + rwl] = xin[sB][rwl + 1][cw];
        });

        // E: partials over my 16 ci for all 8 w — every register-array index is
        //    a compile-time constant (frontend-expanded), so wreg/acc/xv live in VGPRs
        float acc[8] = {0.f,0.f,0.f,0.f,0.f,0.f,0.f,0.f};
        static_for<3>([&](auto KH) {
            constexpr int kh = KH.value;
            const float* xs = (kh == 0) ? &xin[sA][0][0]
                            : (kh == 1) ? &xin[sB][0][0] : &xin[sC][0][0];
            static_for<10>([&](auto COL) {
                constexpr int col = COL.value;
                float4 a0 = *reinterpret_cast<const float4*>(xs + col*68 + ci0);
                float4 a1 = *reinterpret_cast<const float4*>(xs + col*68 + ci0 + 4);
                float4 a2 = *reinterpret_cast<const float4*>(xs + col*68 + ci0 + 8);
                float4 a3 = *reinterpret_cast<const float4*>(xs + col*68 + ci0 + 12);
                float xv[16];
                xv[0]=a0.x; xv[1]=a0.y; xv[2]=a0.z; xv[3]=a0.w;
                xv[4]=a1.x; xv[5]=a1.y; xv[6]=a1.z; xv[7]=a1.w;
                xv[8]=a2.x; xv[9]=a2.y; xv[10]=a2.z; xv[11]=a2.w;
                xv[12]=a3.x; xv[13]=a3.y; xv[14]=a3.z; xv[15]=a3.w;
                static_for<16>([&](auto I) {
                    constexpr int i = I.value;
                    static_for<3>([&](auto KW) {
                        constexpr int kw = KW.value;
                        constexpr int w = col - kw;
                        if constexpr (w >= 0 && w < 8)
                            acc[w] = fmaf(wreg[i*9 + kh*3 + kw], xv[i], acc[w]);
                    });
                });
            });
        });

        // F: intra-wave reduce-scatter over ci-groups (no LDS, no barrier)
        const bool hiw = (cig & 1) != 0;
        float p0, p1, p2, p3;
        {
            float s0 = hiw ? acc[0] : acc[4];
            float s1 = hiw ? acc[1] : acc[5];
            float s2 = hiw ? acc[2] : acc[6];
            float s3 = hiw ? acc[3] : acc[7];
            float r0 = __shfl_xor(s0, 16, 64);
            float r1 = __shfl_xor(s1, 16, 64);
            float r2 = __shfl_xor(s2, 16, 64);
            float r3 = __shfl_xor(s3, 16, 64);
            p0 = (hiw ? acc[4] : acc[0]) + r0;
            p1 = (hiw ? acc[5] : acc[1]) + r1;
            p2 = (hiw ? acc[6] : acc[2]) + r2;
            p3 = (hiw ? acc[7] : acc[3]) + r3;
        }
        const bool hi2 = (cig & 2) != 0;
        float q0, q1;
        {
            float s0 = hi2 ? p0 : p2;
            float s1 = hi2 ? p1 : p3;
            float r0 = __shfl_xor(s0, 32, 64);
            float r1 = __shfl_xor(s1, 32, 64);
            q0 = (hi2 ? p2 : p0) + r0;
            q1 = (hi2 ? p3 : p1) + r1;
        }
        // q0,q1 = conv sums for w = wlo, wlo+1 at output channel co

        const float y0  = q0 + breg, y1 = q1 + breg;
        const float ov0 = xin[sC][wlo + 1][co];
        const float ov1 = xin[sC][wlo + 2][co];
        const float nv0 = ov0 + tanhf(y0);
        const float nv1 = ov1 + tanhf(y1);

        // edge exports (w==0 lanes: cig0; w==7 lanes: cig3)
        if (cig == 0 && ch > 0)
            __hip_atomic_store(&g_halo[(((b*NCH + ch)*2 + 0)*2 + (pos&1))*Cn + co], nv0, RLX, AGENT);
        if (cig == 3 && ch < NCH - 1)
            __hip_atomic_store(&g_halo[(((b*NCH + ch)*2 + 1)*2 + (pos&1))*Cn + co], nv1, RLX, AGENT);

        // update row pos in LDS (visible to block at SYNC2)
        xin[sC][wlo + 1][co] = nv0;
        xin[sC][wlo + 2][co] = nv1;

        // per-wave release: halo stores complete at coherence point, then flag
        asm volatile("s_waitcnt vmcnt(0)" ::: "memory");
        if (lane == 0 && ch > 0)
            __hip_atomic_store(&g_flagsM[((b*NCH + ch)*2 + 0)*4 + wq], pos, RLX, AGENT);
        if (lane == 48 && ch < NCH - 1)
            __hip_atomic_store(&g_flagsM[((b*NCH + ch)*2 + 1)*4 + wq], pos, RLX, AGENT);

        __syncthreads();  // SYNC2
    }

    // final row Out write
    static_for<2>([&](auto Hh) {
        constexpr int h = Hh.value;
        const int cw = rco + 32*h;
        Ob[(size_t)cw * HWc + (size_t)(Hn-1) * Wn + w0 + rwl] = xin[(Hn-1)%3][rwl + 1][cw];
    });
}

extern "C" void kernel_launch(void* const* d_in, const int* in_sizes, int n_in,
                              void* d_out, int out_size, void* d_ws, size_t ws_size,
                              hipStream_t stream) {
    const float* X    = (const float*)d_in[0];
    const float* Wt   = (const float*)d_in[1];
    const float* Bias = (const float*)d_in[2];
    float*       Out  = (float*)d_out;

    hipLaunchKernelGGL(zero_flags_k, dim3(8), dim3(256), 0, stream);

    void* args[] = {(void*)&X, (void*)&Wt, (void*)&Bias, (void*)&Out};
    hipError_t e = hipLaunchCooperativeKernel((void*)seqconv_k, dim3(Bn*NCH), dim3(256),
                                              args, 0, stream);
    if (e != hipSuccess) {
        hipLaunchKernelGGL(seqconv_k, dim3(Bn*NCH), dim3(256), 0, stream, X, Wt, Bias, Out);
    }
}

// Round 6
// 954.017 us; speedup vs baseline: 1.2422x; 1.2261x over previous
//
#include <hip/hip_runtime.h>
#include <math.h>
#include <utility>

#define Bn  8
#define Cn  64
#define Hn  192
#define Wn  256
#define HWc (Hn*Wn)
#define CHWc (Cn*HWc)
#define NCH 32
#define CWc 8
#define NT  512

#define AGENT __HIP_MEMORY_SCOPE_AGENT
#define RLX   __ATOMIC_RELAXED

template <int... Is, class F>
__device__ __forceinline__ void sf_impl(F&& f, std::integer_sequence<int, Is...>) {
    (f(std::integral_constant<int, Is>{}), ...);
}
template <int N, class F>
__device__ __forceinline__ void static_for(F&& f) {
    sf_impl(f, std::make_integer_sequence<int, N>{});
}

// [b][ch][side][wave 0..7] = last row completed (monotonic); zeroed each launch
__device__ int   g_flagsM[Bn*NCH*2*8];
// [b][ch][side(0=left,1=right)][parity][c]
__device__ float g_halo[Bn*NCH*2*2*Cn];

__global__ void zero_flags_k() {
    int i = blockIdx.x * 256 + threadIdx.x;
    if (i < Bn*NCH*2*8) g_flagsM[i] = 0;
}

// pin 8 weight values as asm-defined: compiler cannot rematerialize them by
// re-loading from Wt inside the loop (the R4 failure mode)
#define PIN8(B) asm volatile("" : "+v"(wreg[B]),"+v"(wreg[B+1]),"+v"(wreg[B+2]),\
    "+v"(wreg[B+3]),"+v"(wreg[B+4]),"+v"(wreg[B+5]),"+v"(wreg[B+6]),"+v"(wreg[B+7]))

__global__ __launch_bounds__(NT, 2) void seqconv_k(
    const float* __restrict__ X, const float* __restrict__ Wt,
    const float* __restrict__ Bias, float* __restrict__ Out)
{
    const int tid  = threadIdx.x;
    const int lane = tid & 63;
    const int wq   = tid >> 6;          // wave 0..7 : co-high
    const int co_l = lane & 7;
    const int cig  = lane >> 3;         // ci-group 0..7 (8 ci each)
    const int co   = wq * 8 + co_l;
    const int ci0  = cig * 8;
    const int bid  = blockIdx.x;
    const int b    = bid & 7;           // batch -> same XCD for all chunks of b
    const int ch   = bid >> 3;          // width chunk 0..31
    const int w0   = ch * CWc;
    const int co_d = tid >> 3, wl_d = tid & 7;   // Out-write mapping
    // final w owned by this lane after 3-level reduce-scatter
    const int wfin = 4*(cig & 1) + 2*((cig >> 1) & 1) + ((cig >> 2) & 1);

    __shared__ __align__(16) float xin[3][12][68];  // [slot][col 0..9][ci]
    float* const xinf = &xin[0][0][0];

    const float* Xb = X  + (size_t)b * CHWc;
    float*       Ob = Out + (size_t)b * CHWc;

    // ---- weights -> registers: 72 contiguous floats (co,ci0..ci0+7,3,3)
    float wreg[72];
    {
        const float4* wsrc = reinterpret_cast<const float4*>(Wt + (size_t)co * 576 + ci0 * 9);
        static_for<18>([&](auto T) {
            constexpr int t = T.value;
            float4 v = wsrc[t];
            wreg[4*t] = v.x; wreg[4*t+1] = v.y; wreg[4*t+2] = v.z; wreg[4*t+3] = v.w;
        });
    }
    PIN8(0); PIN8(8); PIN8(16); PIN8(24); PIN8(32); PIN8(40); PIN8(48); PIN8(56); PIN8(64);
    const float breg = Bias[co];

    // ---- staging tuples: 640 = 64ci x 10col over 512 threads (2 rounds)
    int  l_off[2], x_off[2];
    bool s_act[2], s_ok[2];
    static_for<2>([&](auto K) {
        constexpr int k = K.value;
        int idx = tid + NT*k;
        bool act = idx < 640;
        int ci  = act ? idx / 10 : 0;
        int col = act ? idx % 10 : 0;
        int gw  = w0 - 1 + col;
        bool ok = act && gw >= 0 && gw < Wn;
        s_act[k] = act; s_ok[k] = ok;
        l_off[k] = col*68 + ci;
        x_off[k] = ci*HWc + (ok ? gw : 0);
    });

    // ---- rows 0,1 -> slots 0,1 (original == updated); copy Out rows 0,1
    static_for<2>([&](auto R) {
        constexpr int r = R.value;
        static_for<2>([&](auto K) {
            constexpr int k = K.value;
            if (s_act[k]) xinf[r*816 + l_off[k]] = s_ok[k] ? Xb[x_off[k] + r*Wn] : 0.f;
        });
    });
    for (int idx = tid; idx < 2*Cn*CWc; idx += NT) {
        int r = idx >> 9, rem = idx & 511, c = rem >> 3, wl = rem & 7;
        size_t o = (size_t)c * HWc + (size_t)r * Wn + w0 + wl;
        Ob[o] = Xb[o];
    }

    // prefetch original row 2
    float pf0 = s_ok[0] ? Xb[x_off[0] + 2*Wn] : 0.f;
    float pf1 = s_ok[1] ? Xb[x_off[1] + 2*Wn] : 0.f;

    __syncthreads();

    for (int pos = 2; pos < Hn; ++pos) {
        const int sA = (pos - 2) % 3, sB = (pos - 1) % 3, sC = pos % 3;

        // A: commit prefetched original row pos
        if (s_act[0]) xinf[sC*816 + l_off[0]] = pf0;
        if (s_act[1]) xinf[sC*816 + l_off[1]] = pf1;

        // C: issue next-row prefetch BEFORE the poll (HBM latency overlaps stall)
        {
            const int nr = (pos + 1 < Hn) ? pos + 1 : pos;
            pf0 = s_ok[0] ? Xb[x_off[0] + nr*Wn] : 0.f;
            pf1 = s_ok[1] ? Xb[x_off[1] + nr*Wn] : 0.f;
        }

        // B: wave0 polls left neighbor, wave1 polls right; pull halo row pos-1
        if (pos >= 3) {
            if (tid < 64) {
                if (ch > 0) {
                    const int fb = ((b*NCH + ch - 1)*2 + 1)*8;  // left nb, right edge
                    int f;
                    do { f = __hip_atomic_load(&g_flagsM[fb + (lane & 7)], RLX, AGENT); }
                    while (!__all(f >= pos - 1));
                    xin[sB][0][lane] = __hip_atomic_load(
                        &g_halo[(((b*NCH + ch - 1)*2 + 1)*2 + ((pos-1)&1))*Cn + lane], RLX, AGENT);
                }
            } else if (tid < 128) {
                if (ch < NCH - 1) {
                    const int fb = ((b*NCH + ch + 1)*2 + 0)*8;  // right nb, left edge
                    int f;
                    do { f = __hip_atomic_load(&g_flagsM[fb + (lane & 7)], RLX, AGENT); }
                    while (!__all(f >= pos - 1));
                    xin[sB][9][lane] = __hip_atomic_load(
                        &g_halo[(((b*NCH + ch + 1)*2 + 0)*2 + ((pos-1)&1))*Cn + lane], RLX, AGENT);
                }
            }
        }
        __syncthreads();  // SYNC1

        // D: deferred coalesced Out write of row pos-1 (interior cols only)
        Ob[(size_t)co_d * HWc + (size_t)(pos-1) * Wn + w0 + wl_d] = xinf[sB*816 + (wl_d+1)*68 + co_d];

        // E: partials over my 8 ci for all 8 w (weights pinned in VGPRs)
        float acc[8] = {0.f,0.f,0.f,0.f,0.f,0.f,0.f,0.f};
        static_for<3>([&](auto KH) {
            constexpr int kh = KH.value;
            const float* bp = xinf + (kh == 0 ? sA : kh == 1 ? sB : sC)*816 + ci0;
            static_for<10>([&](auto COL) {
                constexpr int col = COL.value;
                float4 a0 = *reinterpret_cast<const float4*>(bp + col*68);
                float4 a1 = *reinterpret_cast<const float4*>(bp + col*68 + 4);
                float xv[8];
                xv[0]=a0.x; xv[1]=a0.y; xv[2]=a0.z; xv[3]=a0.w;
                xv[4]=a1.x; xv[5]=a1.y; xv[6]=a1.z; xv[7]=a1.w;
                static_for<8>([&](auto I) {
                    constexpr int i = I.value;
                    static_for<3>([&](auto KW) {
                        constexpr int kw = KW.value;
                        constexpr int w = col - kw;
                        if constexpr (w >= 0 && w < 8)
                            acc[w] = fmaf(wreg[i*9 + kh*3 + kw], xv[i], acc[w]);
                    });
                });
            });
        });

        // F: 3-level intra-wave reduce-scatter over 8 ci-groups
        float p[4], q[2], fsum;
        {
            const bool hb = (cig & 1) != 0;
            static_for<4>([&](auto J) {
                constexpr int j = J.value;
                float s = hb ? acc[j] : acc[j+4];
                float r = __shfl_xor(s, 8, 64);
                p[j] = (hb ? acc[j+4] : acc[j]) + r;
            });
        }
        {
            const bool hb = (cig & 2) != 0;
            static_for<2>([&](auto J) {
                constexpr int j = J.value;
                float s = hb ? p[j] : p[j+2];
                float r = __shfl_xor(s, 16, 64);
                q[j] = (hb ? p[j+2] : p[j]) + r;
            });
        }
        {
            const bool hb = (cig & 4) != 0;
            float s = hb ? q[0] : q[1];
            float r = __shfl_xor(s, 32, 64);
            fsum = (hb ? q[1] : q[0]) + r;
        }
        // fsum = conv sum for (w = wfin, channel co)

        const float y  = fsum + breg;
        const float ov = xinf[sC*816 + (wfin+1)*68 + co];
        const float nv = ov + tanhf(y);

        // edge exports (w==0 -> cig==0 ; w==7 -> cig==7)
        if (cig == 0 && ch > 0)
            __hip_atomic_store(&g_halo[(((b*NCH + ch)*2 + 0)*2 + (pos&1))*Cn + co], nv, RLX, AGENT);
        if (cig == 7 && ch < NCH - 1)
            __hip_atomic_store(&g_halo[(((b*NCH + ch)*2 + 1)*2 + (pos&1))*Cn + co], nv, RLX, AGENT);

        // update row pos in LDS (one writer per (w,co))
        xinf[sC*816 + (wfin+1)*68 + co] = nv;

        // per-wave release: drain stores to coherence point, then monotonic flag
        asm volatile("s_waitcnt vmcnt(0)" ::: "memory");
        if (lane == 0 && ch > 0)
            __hip_atomic_store(&g_flagsM[((b*NCH + ch)*2 + 0)*8 + wq], pos, RLX, AGENT);
        if (lane == 1 && ch < NCH - 1)
            __hip_atomic_store(&g_flagsM[((b*NCH + ch)*2 + 1)*8 + wq], pos, RLX, AGENT);

        __syncthreads();  // SYNC2
    }

    // final row Out write
    Ob[(size_t)co_d * HWc + (size_t)(Hn-1) * Wn + w0 + wl_d] =
        xinf[((Hn-1)%3)*816 + (wl_d+1)*68 + co_d];
}

extern "C" void kernel_launch(void* const* d_in, const int* in_sizes, int n_in,
                              void* d_out, int out_size, void* d_ws, size_t ws_size,
                              hipStream_t stream) {
    const float* X    = (const float*)d_in[0];
    const float* Wt   = (const float*)d_in[1];
    const float* Bias = (const float*)d_in[2];
    float*       Out  = (float*)d_out;

    hipLaunchKernelGGL(zero_flags_k, dim3(16), dim3(256), 0, stream);

    void* args[] = {(void*)&X, (void*)&Wt, (void*)&Bias, (void*)&Out};
    hipError_t e = hipLaunchCooperativeKernel((void*)seqconv_k, dim3(Bn*NCH), dim3(NT),
                                              args, 0, stream);
    if (e != hipSuccess) {
        hipLaunchKernelGGL(seqconv_k, dim3(Bn*NCH), dim3(NT), 0, stream, X, Wt, Bias, Out);
    }
}

// Round 9
// 856.393 us; speedup vs baseline: 1.3838x; 1.1140x over previous
//
#include <hip/hip_runtime.h>
#include <math.h>
#include <utility>

#define Bn  8
#define Cn  64
#define Hn  192
#define Wn  256
#define HWc (Hn*Wn)
#define CHWc (Cn*HWc)
#define NCH 32
#define CWc 8
#define NT  512

#define AGENT __HIP_MEMORY_SCOPE_AGENT
#define RLX   __ATOMIC_RELAXED

template <int... Is, class F>
__device__ __forceinline__ void sf_impl(F&& f, std::integer_sequence<int, Is...>) {
    (f(std::integral_constant<int, Is>{}), ...);
}
template <int N, class F>
__device__ __forceinline__ void static_for(F&& f) {
    sf_impl(f, std::make_integer_sequence<int, N>{});
}

// [b][ch][side][wave 0..7] = last row completed (monotonic); zeroed each launch
__device__ int   g_flagsM[Bn*NCH*2*8];
// [b][ch][side(0=left,1=right)][parity][c]
__device__ float g_halo[Bn*NCH*2*2*Cn];

__global__ void zero_flags_k() {
    int i = blockIdx.x * 256 + threadIdx.x;
    if (i < Bn*NCH*2*8) g_flagsM[i] = 0;
}

// pin 8 weight values as asm-defined: compiler cannot rematerialize them by
// re-loading from Wt inside the loop
#define PIN8(B) asm volatile("" : "+v"(wreg[B]),"+v"(wreg[B+1]),"+v"(wreg[B+2]),\
    "+v"(wreg[B+3]),"+v"(wreg[B+4]),"+v"(wreg[B+5]),"+v"(wreg[B+6]),"+v"(wreg[B+7]))

// waves_per_eu(2,2): grid is exactly 1 block/CU (8 waves = 2/EU) by design, so
// tell the allocator NOT to squeeze VGPRs for unreachable occupancy (R6: it
// capped at 64 VGPRs and spilled the 72 pinned weights -> ~1us/step of moves)
__global__ __launch_bounds__(NT)
__attribute__((amdgpu_waves_per_eu(2, 2)))
void seqconv_k(
    const float* __restrict__ X, const float* __restrict__ Wt,
    const float* __restrict__ Bias, float* __restrict__ Out)
{
    const int tid  = threadIdx.x;
    const int lane = tid & 63;
    const int wq   = tid >> 6;          // wave 0..7 : co-high
    const int co_l = lane & 7;
    const int cig  = lane >> 3;         // ci-group 0..7 (8 ci each)
    const int co   = wq * 8 + co_l;
    const int ci0  = cig * 8;
    const int bid  = blockIdx.x;
    const int b    = bid & 7;           // batch -> same XCD for all chunks of b
    const int ch   = bid >> 3;          // width chunk 0..31
    const int w0   = ch * CWc;
    const int co_d = tid >> 3, wl_d = tid & 7;   // Out-write mapping
    // final w owned by this lane after 3-level reduce-scatter
    const int wfin = 4*(cig & 1) + 2*((cig >> 1) & 1) + ((cig >> 2) & 1);

    __shared__ __align__(16) float xin[3][12][68];  // [slot][col 0..9][ci]
    float* const xinf = &xin[0][0][0];

    const float* Xb = X  + (size_t)b * CHWc;
    float*       Ob = Out + (size_t)b * CHWc;

    // ---- weights -> registers: 72 contiguous floats (co,ci0..ci0+7,3,3)
    float wreg[72];
    {
        const float4* wsrc = reinterpret_cast<const float4*>(Wt + (size_t)co * 576 + ci0 * 9);
        static_for<18>([&](auto T) {
            constexpr int t = T.value;
            float4 v = wsrc[t];
            wreg[4*t] = v.x; wreg[4*t+1] = v.y; wreg[4*t+2] = v.z; wreg[4*t+3] = v.w;
        });
    }
    PIN8(0); PIN8(8); PIN8(16); PIN8(24); PIN8(32); PIN8(40); PIN8(48); PIN8(56); PIN8(64);
    const float breg = Bias[co];

    // ---- staging tuples: 640 = 64ci x 10col over 512 threads (2 rounds)
    int  l_off[2], x_off[2];
    bool s_act[2], s_ok[2];
    static_for<2>([&](auto K) {
        constexpr int k = K.value;
        int idx = tid + NT*k;
        bool act = idx < 640;
        int ci  = act ? idx / 10 : 0;
        int col = act ? idx % 10 : 0;
        int gw  = w0 - 1 + col;
        bool ok = act && gw >= 0 && gw < Wn;
        s_act[k] = act; s_ok[k] = ok;
        l_off[k] = col*68 + ci;
        x_off[k] = ci*HWc + (ok ? gw : 0);
    });

    // ---- rows 0,1 -> slots 0,1 (original == updated); copy Out rows 0,1
    static_for<2>([&](auto R) {
        constexpr int r = R.value;
        static_for<2>([&](auto K) {
            constexpr int k = K.value;
            if (s_act[k]) xinf[r*816 + l_off[k]] = s_ok[k] ? Xb[x_off[k] + r*Wn] : 0.f;
        });
    });
    for (int idx = tid; idx < 2*Cn*CWc; idx += NT) {
        int r = idx >> 9, rem = idx & 511, c = rem >> 3, wl = rem & 7;
        size_t o = (size_t)c * HWc + (size_t)r * Wn + w0 + wl;
        Ob[o] = Xb[o];
    }

    // prefetch original row 2
    float pf0 = s_ok[0] ? Xb[x_off[0] + 2*Wn] : 0.f;
    float pf1 = s_ok[1] ? Xb[x_off[1] + 2*Wn] : 0.f;

    __syncthreads();

    for (int pos = 2; pos < Hn; ++pos) {
        const int sA = (pos - 2) % 3, sB = (pos - 1) % 3, sC = pos % 3;

        // A: commit prefetched original row pos
        if (s_act[0]) xinf[sC*816 + l_off[0]] = pf0;
        if (s_act[1]) xinf[sC*816 + l_off[1]] = pf1;

        // C: issue next-row prefetch BEFORE the poll (HBM latency overlaps stall)
        {
            const int nr = (pos + 1 < Hn) ? pos + 1 : pos;
            pf0 = s_ok[0] ? Xb[x_off[0] + nr*Wn] : 0.f;
            pf1 = s_ok[1] ? Xb[x_off[1] + nr*Wn] : 0.f;
        }

        // B: wave0 polls left neighbor, wave1 polls right; pull halo row pos-1
        if (pos >= 3) {
            if (tid < 64) {
                if (ch > 0) {
                    const int fb = ((b*NCH + ch - 1)*2 + 1)*8;  // left nb, right edge
                    int f;
                    do { f = __hip_atomic_load(&g_flagsM[fb + (lane & 7)], RLX, AGENT); }
                    while (!__all(f >= pos - 1));
                    xin[sB][0][lane] = __hip_atomic_load(
                        &g_halo[(((b*NCH + ch - 1)*2 + 1)*2 + ((pos-1)&1))*Cn + lane], RLX, AGENT);
                }
            } else if (tid < 128) {
                if (ch < NCH - 1) {
                    const int fb = ((b*NCH + ch + 1)*2 + 0)*8;  // right nb, left edge
                    int f;
                    do { f = __hip_atomic_load(&g_flagsM[fb + (lane & 7)], RLX, AGENT); }
                    while (!__all(f >= pos - 1));
                    xin[sB][9][lane] = __hip_atomic_load(
                        &g_halo[(((b*NCH + ch + 1)*2 + 0)*2 + ((pos-1)&1))*Cn + lane], RLX, AGENT);
                }
            }
        }
        __syncthreads();  // SYNC1

        // D: deferred coalesced Out write of row pos-1 (interior cols only)
        Ob[(size_t)co_d * HWc + (size_t)(pos-1) * Wn + w0 + wl_d] = xinf[sB*816 + (wl_d+1)*68 + co_d];

        // E: partials over my 8 ci for all 8 w (weights pinned in VGPRs)
        float acc[8] = {0.f,0.f,0.f,0.f,0.f,0.f,0.f,0.f};
        static_for<3>([&](auto KH) {
            constexpr int kh = KH.value;
            const float* bp = xinf + (kh == 0 ? sA : kh == 1 ? sB : sC)*816 + ci0;
            static_for<10>([&](auto COL) {
                constexpr int col = COL.value;
                float4 a0 = *reinterpret_cast<const float4*>(bp + col*68);
                float4 a1 = *reinterpret_cast<const float4*>(bp + col*68 + 4);
                float xv[8];
                xv[0]=a0.x; xv[1]=a0.y; xv[2]=a0.z; xv[3]=a0.w;
                xv[4]=a1.x; xv[5]=a1.y; xv[6]=a1.z; xv[7]=a1.w;
                static_for<8>([&](auto I) {
                    constexpr int i = I.value;
                    static_for<3>([&](auto KW) {
                        constexpr int kw = KW.value;
                        constexpr int w = col - kw;
                        if constexpr (w >= 0 && w < 8)
                            acc[w] = fmaf(wreg[i*9 + kh*3 + kw], xv[i], acc[w]);
                    });
                });
            });
        });

        // F: 3-level intra-wave reduce-scatter over 8 ci-groups
        float p[4], q[2], fsum;
        {
            const bool hb = (cig & 1) != 0;
            static_for<4>([&](auto J) {
                constexpr int j = J.value;
                float s = hb ? acc[j] : acc[j+4];
                float r = __shfl_xor(s, 8, 64);
                p[j] = (hb ? acc[j+4] : acc[j]) + r;
            });
        }
        {
            const bool hb = (cig & 2) != 0;
            static_for<2>([&](auto J) {
                constexpr int j = J.value;
                float s = hb ? p[j] : p[j+2];
                float r = __shfl_xor(s, 16, 64);
                q[j] = (hb ? p[j+2] : p[j]) + r;
            });
        }
        {
            const bool hb = (cig & 4) != 0;
            float s = hb ? q[0] : q[1];
            float r = __shfl_xor(s, 32, 64);
            fsum = (hb ? q[1] : q[0]) + r;
        }
        // fsum = conv sum for (w = wfin, channel co)

        const float y  = fsum + breg;
        const float ov = xinf[sC*816 + (wfin+1)*68 + co];
        const float nv = ov + tanhf(y);

        // edge exports (w==0 -> cig==0 ; w==7 -> cig==7)
        if (cig == 0 && ch > 0)
            __hip_atomic_store(&g_halo[(((b*NCH + ch)*2 + 0)*2 + (pos&1))*Cn + co], nv, RLX, AGENT);
        if (cig == 7 && ch < NCH - 1)
            __hip_atomic_store(&g_halo[(((b*NCH + ch)*2 + 1)*2 + (pos&1))*Cn + co], nv, RLX, AGENT);

        // update row pos in LDS (one writer per (w,co))
        xinf[sC*816 + (wfin+1)*68 + co] = nv;

        // per-wave release: drain stores to coherence point, then monotonic flag
        asm volatile("s_waitcnt vmcnt(0)" ::: "memory");
        if (lane == 0 && ch > 0)
            __hip_atomic_store(&g_flagsM[((b*NCH + ch)*2 + 0)*8 + wq], pos, RLX, AGENT);
        if (lane == 1 && ch < NCH - 1)
            __hip_atomic_store(&g_flagsM[((b*NCH + ch)*2 + 1)*8 + wq], pos, RLX, AGENT);

        __syncthreads();  // SYNC2
    }

    // final row Out write
    Ob[(size_t)co_d * HWc + (size_t)(Hn-1) * Wn + w0 + wl_d] =
        xinf[((Hn-1)%3)*816 + (wl_d+1)*68 + co_d];
}

extern "C" void kernel_launch(void* const* d_in, const int* in_sizes, int n_in,
                              void* d_out, int out_size, void* d_ws, size_t ws_size,
                              hipStream_t stream) {
    const float* X    = (const float*)d_in[0];
    const float* Wt   = (const float*)d_in[1];
    const float* Bias = (const float*)d_in[2];
    float*       Out  = (float*)d_out;

    hipLaunchKernelGGL(zero_flags_k, dim3(16), dim3(256), 0, stream);

    void* args[] = {(void*)&X, (void*)&Wt, (void*)&Bias, (void*)&Out};
    hipError_t e = hipLaunchCooperativeKernel((void*)seqconv_k, dim3(Bn*NCH), dim3(NT),
                                              args, 0, stream);
    if (e != hipSuccess) {
        hipLaunchKernelGGL(seqconv_k, dim3(Bn*NCH), dim3(NT), 0, stream, X, Wt, Bias, Out);
    }
}

// Round 10
// 829.440 us; speedup vs baseline: 1.4287x; 1.0325x over previous
//
#include <hip/hip_runtime.h>
#include <math.h>
#include <utility>

#define Bn  8
#define Cn  64
#define Hn  192
#define Wn  256
#define HWc (Hn*Wn)
#define CHWc (Cn*HWc)
#define NCH 32
#define CWc 8
#define NT  512

#define AGENT __HIP_MEMORY_SCOPE_AGENT
#define RLX   __ATOMIC_RELAXED

template <int... Is, class F>
__device__ __forceinline__ void sf_impl(F&& f, std::integer_sequence<int, Is...>) {
    (f(std::integral_constant<int, Is>{}), ...);
}
template <int N, class F>
__device__ __forceinline__ void static_for(F&& f) {
    sf_impl(f, std::make_integer_sequence<int, N>{});
}

// [b][ch][side][wave 0..7] = last row completed (monotonic); zeroed each launch
__device__ int   g_flagsM[Bn*NCH*2*8];
// [b][ch][side(0=left,1=right)][parity][c]
__device__ float g_halo[Bn*NCH*2*2*Cn];

__global__ void zero_flags_k() {
    int i = blockIdx.x * 256 + threadIdx.x;
    if (i < Bn*NCH*2*8) g_flagsM[i] = 0;
}

// pin weights as asm-defined: no remat-by-reload inside the loop
#define PIN8(B) asm volatile("" : "+v"(wreg[B]),"+v"(wreg[B+1]),"+v"(wreg[B+2]),\
    "+v"(wreg[B+3]),"+v"(wreg[B+4]),"+v"(wreg[B+5]),"+v"(wreg[B+6]),"+v"(wreg[B+7]))

// grid = 1 block/CU (8 waves = 2/EU): tell the allocator not to squeeze for
// unreachable occupancy (R6: 64-VGPR cap spilled weights)
__global__ __launch_bounds__(NT)
__attribute__((amdgpu_waves_per_eu(2, 2)))
void seqconv_k(
    const float* __restrict__ X, const float* __restrict__ Wt,
    const float* __restrict__ Bias, float* __restrict__ Out)
{
    const int tid  = threadIdx.x;
    const int lane = tid & 63;
    const int wq   = tid >> 6;          // wave 0..7
    const int cig  = lane & 15;         // ci-group (4 ci each)
    const int co_s = lane >> 4;         // 0..3
    const int co_lo = wq * 4 + co_s;    // 0..31 ; thread also handles co_lo+32
    const int ci0  = cig * 4;
    const int bid  = blockIdx.x;
    const int b    = bid & 7;           // batch -> same XCD for all chunks of b
    const int ch   = bid >> 3;          // width chunk 0..31
    const int w0   = ch * CWc;
    const int co_d = tid >> 3, wl_d = tid & 7;   // coalesced Out-write mapping
    // after 4-level reduce-scatter, this lane owns (w=wfin, co=co_f)
    const int wfin = cig & 7;
    const int co_f = co_lo + ((cig & 8) ? 32 : 0);

    __shared__ __align__(16) float xin[3][12][68];  // [slot][col 0..9][ci]
    float* const xinf = &xin[0][0][0];

    const float* Xb = X  + (size_t)b * CHWc;
    float*       Ob = Out + (size_t)b * CHWc;

    // ---- weights -> registers: 2 co x 4 ci x 9 = 72 floats, contiguous per co
    float wreg[72];
    static_for<2>([&](auto Bb) {
        constexpr int bb = Bb.value;
        const float4* ws = reinterpret_cast<const float4*>(
            Wt + (size_t)(co_lo + 32*bb) * 576 + ci0 * 9);
        static_for<9>([&](auto T) {
            constexpr int t = T.value;
            float4 v = ws[t];
            wreg[bb*36 + 4*t]   = v.x; wreg[bb*36 + 4*t+1] = v.y;
            wreg[bb*36 + 4*t+2] = v.z; wreg[bb*36 + 4*t+3] = v.w;
        });
    });
    PIN8(0); PIN8(8); PIN8(16); PIN8(24); PIN8(32); PIN8(40); PIN8(48); PIN8(56); PIN8(64);
    const float bv0 = Bias[co_lo], bv1 = Bias[co_lo + 32];
    const float bregf = (cig & 8) ? bv1 : bv0;

    // ---- staging tuples: 640 = 64ci x 10col over 512 threads (2 rounds)
    int  l_off[2], x_off[2];
    bool s_act[2], s_ok[2];
    static_for<2>([&](auto K) {
        constexpr int k = K.value;
        int idx = tid + NT*k;
        bool act = idx < 640;
        int ci  = act ? idx / 10 : 0;
        int col = act ? idx % 10 : 0;
        int gw  = w0 - 1 + col;
        bool ok = act && gw >= 0 && gw < Wn;
        s_act[k] = act; s_ok[k] = ok;
        l_off[k] = col*68 + ci;
        x_off[k] = ci*HWc + (ok ? gw : 0);
    });

    // ---- rows 0,1 -> slots 0,1 (original == updated); copy Out rows 0,1
    static_for<2>([&](auto R) {
        constexpr int r = R.value;
        static_for<2>([&](auto K) {
            constexpr int k = K.value;
            if (s_act[k]) xinf[r*816 + l_off[k]] = s_ok[k] ? Xb[x_off[k] + r*Wn] : 0.f;
        });
    });
    for (int idx = tid; idx < 2*Cn*CWc; idx += NT) {
        int r = idx >> 9, rem = idx & 511, c = rem >> 3, wl = rem & 7;
        size_t o = (size_t)c * HWc + (size_t)r * Wn + w0 + wl;
        Ob[o] = Xb[o];
    }

    // prefetch original row 2
    float pf0 = s_ok[0] ? Xb[x_off[0] + 2*Wn] : 0.f;
    float pf1 = s_ok[1] ? Xb[x_off[1] + 2*Wn] : 0.f;

    __syncthreads();

    // ---- prime the sA register cache with row 0 (slot 0)
    float cA[40];
    static_for<10>([&](auto COL) {
        constexpr int col = COL.value;
        const float4 v = *reinterpret_cast<const float4*>(xinf + col*68 + ci0);
        cA[col*4]   = v.x; cA[col*4+1] = v.y;
        cA[col*4+2] = v.z; cA[col*4+3] = v.w;
    });

    for (int pos = 2; pos < Hn; ++pos) {
        const int sB = (pos - 1) % 3, sC = pos % 3;

        // A: commit prefetched original row pos
        if (s_act[0]) xinf[sC*816 + l_off[0]] = pf0;
        if (s_act[1]) xinf[sC*816 + l_off[1]] = pf1;

        // C: issue next-row prefetch BEFORE the poll (HBM latency overlaps stall)
        {
            const int nr = (pos + 1 < Hn) ? pos + 1 : pos;
            pf0 = s_ok[0] ? Xb[x_off[0] + nr*Wn] : 0.f;
            pf1 = s_ok[1] ? Xb[x_off[1] + nr*Wn] : 0.f;
        }

        // B: wave0 polls left neighbor, wave1 polls right; pull halo row pos-1
        if (pos >= 3) {
            if (tid < 64) {
                if (ch > 0) {
                    const int fb = ((b*NCH + ch - 1)*2 + 1)*8;  // left nb, right edge
                    int f;
                    do { f = __hip_atomic_load(&g_flagsM[fb + (lane & 7)], RLX, AGENT); }
                    while (!__all(f >= pos - 1));
                    xin[sB][0][lane] = __hip_atomic_load(
                        &g_halo[(((b*NCH + ch - 1)*2 + 1)*2 + ((pos-1)&1))*Cn + lane], RLX, AGENT);
                }
            } else if (tid < 128) {
                if (ch < NCH - 1) {
                    const int fb = ((b*NCH + ch + 1)*2 + 0)*8;  // right nb, left edge
                    int f;
                    do { f = __hip_atomic_load(&g_flagsM[fb + (lane & 7)], RLX, AGENT); }
                    while (!__all(f >= pos - 1));
                    xin[sB][9][lane] = __hip_atomic_load(
                        &g_halo[(((b*NCH + ch + 1)*2 + 0)*2 + ((pos-1)&1))*Cn + lane], RLX, AGENT);
                }
            }
        }
        __syncthreads();  // SYNC1

        // D: deferred coalesced Out write of row pos-1
        Ob[(size_t)co_d * HWc + (size_t)(pos-1) * Wn + w0 + wl_d] =
            xinf[sB*816 + (wl_d+1)*68 + co_d];

        // E: partials — kh0 from register cache cA, kh1/kh2 from LDS (1 b128 each).
        //    acc[F] with F = b*8 + w  (b: co_lo vs co_lo+32)
        float acc[16] = {0.f,0.f,0.f,0.f,0.f,0.f,0.f,0.f,
                         0.f,0.f,0.f,0.f,0.f,0.f,0.f,0.f};
        static_for<10>([&](auto COL) {
            constexpr int col = COL.value;
            const float4 xb = *reinterpret_cast<const float4*>(xinf + sB*816 + col*68 + ci0);
            const float4 xc = *reinterpret_cast<const float4*>(xinf + sC*816 + col*68 + ci0);
            float xbv[4], xcv[4], xav[4];
            xbv[0]=xb.x; xbv[1]=xb.y; xbv[2]=xb.z; xbv[3]=xb.w;
            xcv[0]=xc.x; xcv[1]=xc.y; xcv[2]=xc.z; xcv[3]=xc.w;
            static_for<4>([&](auto I) { xav[I.value] = cA[col*4 + I.value]; });
            static_for<3>([&](auto KW) {
                constexpr int kw = KW.value;
                constexpr int w = col - kw;
                if constexpr (w >= 0 && w < 8) {
                    static_for<2>([&](auto Bb) {
                        constexpr int bb = Bb.value;
                        static_for<4>([&](auto I) {
                            constexpr int i = I.value;
                            acc[bb*8+w] = fmaf(wreg[bb*36 + i*9 + 0*3 + kw], xav[i], acc[bb*8+w]);
                            acc[bb*8+w] = fmaf(wreg[bb*36 + i*9 + 1*3 + kw], xbv[i], acc[bb*8+w]);
                            acc[bb*8+w] = fmaf(wreg[bb*36 + i*9 + 2*3 + kw], xcv[i], acc[bb*8+w]);
                        });
                    });
                }
            });
            // this step's sB (updated row pos-1) becomes next step's sA
            static_for<4>([&](auto I) { cA[col*4 + I.value] = xbv[I.value]; });
        });

        // F: 4-level reduce-scatter over 16 ci-groups (keep F-bit == own cig-bit)
        const bool h0 = (cig & 1) != 0, h1 = (cig & 2) != 0;
        const bool h2 = (cig & 4) != 0, h3 = (cig & 8) != 0;
        float r8[8];
        static_for<8>([&](auto J) {
            constexpr int j = J.value;
            float snd = h0 ? acc[2*j]   : acc[2*j+1];
            float kp  = h0 ? acc[2*j+1] : acc[2*j];
            r8[j] = kp + __shfl_xor(snd, 1, 64);
        });
        float r4[4];
        static_for<4>([&](auto J) {
            constexpr int j = J.value;
            float snd = h1 ? r8[2*j]   : r8[2*j+1];
            float kp  = h1 ? r8[2*j+1] : r8[2*j];
            r4[j] = kp + __shfl_xor(snd, 2, 64);
        });
        float r2[2];
        static_for<2>([&](auto J) {
            constexpr int j = J.value;
            float snd = h2 ? r4[2*j]   : r4[2*j+1];
            float kp  = h2 ? r4[2*j+1] : r4[2*j];
            r2[j] = kp + __shfl_xor(snd, 4, 64);
        });
        float snd3 = h3 ? r2[0] : r2[1];
        float kp3  = h3 ? r2[1] : r2[0];
        const float fsum = kp3 + __shfl_xor(snd3, 8, 64);
        // fsum = conv sum for (w = wfin, channel co_f)

        const float y  = fsum + bregf;
        const float ov = xinf[sC*816 + (wfin+1)*68 + co_f];
        const float nv = ov + tanhf(y);

        // edge exports (w==0 / w==7 lanes cover all 64 co across cig 0/8, 7/15)
        if (wfin == 0 && ch > 0)
            __hip_atomic_store(&g_halo[(((b*NCH + ch)*2 + 0)*2 + (pos&1))*Cn + co_f], nv, RLX, AGENT);
        if (wfin == 7 && ch < NCH - 1)
            __hip_atomic_store(&g_halo[(((b*NCH + ch)*2 + 1)*2 + (pos&1))*Cn + co_f], nv, RLX, AGENT);

        // update row pos in LDS (one writer per (w,co))
        xinf[sC*816 + (wfin+1)*68 + co_f] = nv;

        // per-wave release: drain stores to coherence point, then monotonic flag
        asm volatile("s_waitcnt vmcnt(0)" ::: "memory");
        if (lane == 0 && ch > 0)
            __hip_atomic_store(&g_flagsM[((b*NCH + ch)*2 + 0)*8 + wq], pos, RLX, AGENT);
        if (lane == 1 && ch < NCH - 1)
            __hip_atomic_store(&g_flagsM[((b*NCH + ch)*2 + 1)*8 + wq], pos, RLX, AGENT);

        __syncthreads();  // SYNC2
    }

    // final row Out write
    Ob[(size_t)co_d * HWc + (size_t)(Hn-1) * Wn + w0 + wl_d] =
        xinf[((Hn-1)%3)*816 + (wl_d+1)*68 + co_d];
}

extern "C" void kernel_launch(void* const* d_in, const int* in_sizes, int n_in,
                              void* d_out, int out_size, void* d_ws, size_t ws_size,
                              hipStream_t stream) {
    const float* X    = (const float*)d_in[0];
    const float* Wt   = (const float*)d_in[1];
    const float* Bias = (const float*)d_in[2];
    float*       Out  = (float*)d_out;

    hipLaunchKernelGGL(zero_flags_k, dim3(16), dim3(256), 0, stream);

    void* args[] = {(void*)&X, (void*)&Wt, (void*)&Bias, (void*)&Out};
    hipError_t e = hipLaunchCooperativeKernel((void*)seqconv_k, dim3(Bn*NCH), dim3(NT),
                                              args, 0, stream);
    if (e != hipSuccess) {
        hipLaunchKernelGGL(seqconv_k, dim3(Bn*NCH), dim3(NT), 0, stream, X, Wt, Bias, Out);
    }
}